// Round 23
// baseline (170.223 us; speedup 1.0000x reference)
//
#include <hip/hip_runtime.h>
#include <hip/hip_bf16.h>

#define NROWS 65536
#define KDIM  512
constexpr float BN_EPS = 1e-5f;

using short8 = __attribute__((ext_vector_type(8))) short;
using f32x4  = __attribute__((ext_vector_type(4))) float;

#define BM 128   // rows per block; 512 blocks; 2 blocks/CU

// async global->LDS, 16B per lane (dest MUST be uniform base + lane*16 — m104)
__device__ __forceinline__ void gload_lds16(const void* g, void* l) {
  __builtin_amdgcn_global_load_lds(
      (const __attribute__((address_space(1))) void*)g,
      (__attribute__((address_space(3))) void*)l, 16, 0, 0);
}

__device__ __forceinline__ short bf16bits(float x) {
  __hip_bfloat16 h = __float2bfloat16(x);    // RNE
  return *reinterpret_cast<short*>(&h);
}
__device__ __forceinline__ short8 cvt8(const float4& a, const float4& b) {
  short8 h;
  h[0] = bf16bits(a.x); h[1] = bf16bits(a.y); h[2] = bf16bits(a.z); h[3] = bf16bits(a.w);
  h[4] = bf16bits(b.x); h[5] = bf16bits(b.y); h[6] = bf16bits(b.z); h[7] = bf16bits(b.w);
  return h;
}

// ---------------- prep: C1 -> fragment-tiled bf16 (RNE) ----------------
// entry e = kg*512 + col holds C1[kg*8 + i][col], i=0..7 (one B-fragment).
__global__ __launch_bounds__(256)
void prep_c1(const float* __restrict__ C1, short8* __restrict__ c1tH) {
  const int e   = blockIdx.x * 256 + threadIdx.x;   // 0..32767
  const int col = e & 511;
  const int kg  = e >> 9;
  short8 hi;
  #pragma unroll
  for (int i = 0; i < 8; ++i)
    hi[i] = bf16bits(C1[(size_t)(kg * 8 + i) * KDIM + col]);   // coalesced
  c1tH[e] = hi;
}

// ---------------- quad: A-direct-to-reg + B-only LDS, 8 waves/SIMD ----------------
// quad[n] = x_n^T C1 x_n (1-pass bf16 16x16x32 MFMA), fused column stats.
// 16 waves = 2 row-groups (64 rows... wr*32 blocks of 32) x 8 col-groups
// (64 cols each); wave tile 32x64 -> acc = 32 regs (no spill possible).
// A never touches LDS: direct global->VGPR (2-phase ping-pong, cvt in reg).
// B double-buffered in LDS via global_load_lds (2 loads/thread/phase),
// issued at phase top; vmcnt(0)+barrier at phase end (B is L2-resident,
// latency << phase compute -> drain ~0). LDS 68.5 KB -> 2 blocks/CU ->
// 8 waves/SIMD: max TLP + pipelined A, first time both at once.
__global__ __launch_bounds__(1024)
void quad_kernel(const float* __restrict__ X, const short8* __restrict__ c1tH,
                 float* __restrict__ quad,
                 float* __restrict__ colS1, float* __restrict__ colS2,
                 float* __restrict__ colS3, double* __restrict__ qsumsA) {
  __shared__ short8 Bs[2][2048];      // 2 x 32 KB (bf16 fragment-tiled)
  __shared__ float qPart[8][BM];      // 4 KB
  __shared__ float qLds[BM];          // 0.5 KB

  const int tid  = threadIdx.x;
  const int lane = tid & 63;
  const int w    = tid >> 6;          // wave 0..15
  const int wr   = w >> 3;            // row-group (0..1): rows wr*32..+31... x2 below
  const int wc   = w & 7;             // col-group (0..7): cols wc*64..+63
  const int g    = lane >> 4;         // k-group 0..3
  const int lr   = lane & 15;
  const int bid  = blockIdx.x;
  const int r0   = bid * BM;

  // A direct-load bases: lane (g,lr) reads rows wr*64 + rf*16 + lr? ->
  // wave owns rows wr*64 .. wr*64+31?  Use rf in {0,1}: rows wr*64 + rf*16 + lr
  // covers 32 rows (wr in {0,1} covers rows 0..31,64..95? need 0..127).
  // Correct mapping: wave's 32 rows = wr*32*2? Simplest: wr selects 64-row
  // half; rf selects 16-row slice within the wave's 32 rows at wr*64 + rf*16
  // and wr*64+32+... -> use rows wr*64 + rf*32 + (lane>>4 grouping)? Keep it
  // simple and verified: wave rows = wr*64 + rf*16 + lr for rf in {0,1}
  // covers rows wr*64 .. wr*64+31. Remaining rows wr*64+32..+63 belong to
  // NO wave — wrong. Fix: two row-groups of 64 rows each, waves wr in {0,1},
  // and rf in {0,1} covers 32 rows; we need 64 rows per wr across 8 wc...
  // 16 waves x 32 rows = 512 row-slots / 8 wc = 64 distinct rows per wc pair?
  // Final mapping used: row = (w >> 3) * 64 + rf * 16 + ((w >> 2) & 1) * 32 ... 
  // Simplified and checked below: wrr = w >> 2 (0..3) row-quarter of 32 rows,
  // wcc = w & 3 (0..3) col-quarter of 128 cols.
  const int wrr = w >> 2;             // 0..3: rows wrr*32 .. +31
  const int wcc = w & 3;              // 0..3: cols wcc*128 .. +127
  const float* asrc0 = X + (size_t)(r0 + wrr * 32 + lr) * KDIM + g * 8;
  const float* asrc1 = asrc0 + 16 * KDIM;

#define LOADA(kt, dst)                                  \
  {                                                     \
    dst[0] = *(const float4*)(asrc0 + (kt) * 32);       \
    dst[1] = *(const float4*)(asrc0 + (kt) * 32 + 4);   \
    dst[2] = *(const float4*)(asrc1 + (kt) * 32);       \
    dst[3] = *(const float4*)(asrc1 + (kt) * 32 + 4);   \
  }
#define STAGE_B(bufi, kt)                                                  \
  {                                                                        \
    gload_lds16(c1tH + (kt) * 2048 + tid,        &Bs[bufi][tid]);          \
    gload_lds16(c1tH + (kt) * 2048 + 1024 + tid, &Bs[bufi][1024 + tid]);   \
  }

  f32x4 acc[2][8];                    // [rf][cf] : 32 rows x 128 cols
  #pragma unroll
  for (int rf = 0; rf < 2; ++rf)
    #pragma unroll
    for (int cf = 0; cf < 8; ++cf)
      acc[rf][cf] = (f32x4){0.f, 0.f, 0.f, 0.f};

  float4 ae[4], ao[4];                // A raw ping-pong (static idx after unroll)

  // ---- prologue ----
  LOADA(0, ae);
  STAGE_B(0, 0);
  asm volatile("s_waitcnt vmcnt(0)" ::: "memory");
  __builtin_amdgcn_s_barrier();
  __builtin_amdgcn_sched_barrier(0);

  #pragma unroll
  for (int kt = 0; kt < 16; ++kt) {
    const int buf = kt & 1;
    // ---- phase top: next A (regs) + next B (DMA) ----
    if (kt < 15) {
      if (kt & 1) { LOADA(kt + 1, ae); } else { LOADA(kt + 1, ao); }
      STAGE_B(buf ^ 1, kt + 1);
    }
    // ---- compute kt ----
    short8 A0, A1;
    if (kt & 1) { A0 = cvt8(ao[0], ao[1]); A1 = cvt8(ao[2], ao[3]); }
    else        { A0 = cvt8(ae[0], ae[1]); A1 = cvt8(ae[2], ae[3]); }
    const int fb = g * 512 + wcc * 128 + lr;
    {
      const short8 b0 = Bs[buf][fb];
      const short8 b1 = Bs[buf][fb + 16];
      const short8 b2 = Bs[buf][fb + 32];
      const short8 b3 = Bs[buf][fb + 48];
      acc[0][0] = __builtin_amdgcn_mfma_f32_16x16x32_bf16(A0, b0, acc[0][0], 0, 0, 0);
      acc[1][0] = __builtin_amdgcn_mfma_f32_16x16x32_bf16(A1, b0, acc[1][0], 0, 0, 0);
      acc[0][1] = __builtin_amdgcn_mfma_f32_16x16x32_bf16(A0, b1, acc[0][1], 0, 0, 0);
      acc[1][1] = __builtin_amdgcn_mfma_f32_16x16x32_bf16(A1, b1, acc[1][1], 0, 0, 0);
      acc[0][2] = __builtin_amdgcn_mfma_f32_16x16x32_bf16(A0, b2, acc[0][2], 0, 0, 0);
      acc[1][2] = __builtin_amdgcn_mfma_f32_16x16x32_bf16(A1, b2, acc[1][2], 0, 0, 0);
      acc[0][3] = __builtin_amdgcn_mfma_f32_16x16x32_bf16(A0, b3, acc[0][3], 0, 0, 0);
      acc[1][3] = __builtin_amdgcn_mfma_f32_16x16x32_bf16(A1, b3, acc[1][3], 0, 0, 0);
    }
    {
      const short8 b4 = Bs[buf][fb + 64];
      const short8 b5 = Bs[buf][fb + 80];
      const short8 b6 = Bs[buf][fb + 96];
      const short8 b7 = Bs[buf][fb + 112];
      acc[0][4] = __builtin_amdgcn_mfma_f32_16x16x32_bf16(A0, b4, acc[0][4], 0, 0, 0);
      acc[1][4] = __builtin_amdgcn_mfma_f32_16x16x32_bf16(A1, b4, acc[1][4], 0, 0, 0);
      acc[0][5] = __builtin_amdgcn_mfma_f32_16x16x32_bf16(A0, b5, acc[0][5], 0, 0, 0);
      acc[1][5] = __builtin_amdgcn_mfma_f32_16x16x32_bf16(A1, b5, acc[1][5], 0, 0, 0);
      acc[0][6] = __builtin_amdgcn_mfma_f32_16x16x32_bf16(A0, b6, acc[0][6], 0, 0, 0);
      acc[1][6] = __builtin_amdgcn_mfma_f32_16x16x32_bf16(A1, b6, acc[1][6], 0, 0, 0);
      acc[0][7] = __builtin_amdgcn_mfma_f32_16x16x32_bf16(A0, b7, acc[0][7], 0, 0, 0);
      acc[1][7] = __builtin_amdgcn_mfma_f32_16x16x32_bf16(A1, b7, acc[1][7], 0, 0, 0);
    }
    // ---- phase end: drain (B L2-resident; compute covered its latency) ----
    if (kt < 15) {
      asm volatile("s_waitcnt vmcnt(0)" ::: "memory");
      __builtin_amdgcn_s_barrier();
      __builtin_amdgcn_sched_barrier(0);
    }
  }
#undef LOADA
#undef STAGE_B

  // ---- epilogue: row-dot against X for this wave's 128-col slice ----
  #pragma unroll
  for (int rf = 0; rf < 2; ++rf)
    #pragma unroll
    for (int p = 0; p < 4; ++p) {
      const int row = wrr * 32 + rf * 16 + g * 4 + p;
      const float* xr = X + (size_t)(r0 + row) * KDIM + wcc * 128;
      float s = 0.f;
      #pragma unroll
      for (int cf = 0; cf < 8; ++cf)
        s += acc[rf][cf][p] * xr[cf * 16 + lr];
      s += __shfl_xor(s, 1, 64);
      s += __shfl_xor(s, 2, 64);
      s += __shfl_xor(s, 4, 64);
      s += __shfl_xor(s, 8, 64);
      if (lr == 0) {
        // waves (wrr, wcc): 4 col-groups write qPart[wcc][...]; the 4 wrr
        // groups write disjoint row ranges of the same wcc plane.
        qPart[wcc][row] = s;
      }
    }
  __syncthreads();
  if (tid < BM) {
    const float q = qPart[0][tid] + qPart[1][tid] + qPart[2][tid] + qPart[3][tid];
    quad[r0 + tid] = q;
    qLds[tid] = q;
  }
  __syncthreads();
  // ---- fused column stats: 1024 threads = 512 cols x 2 row-halves ----
  {
    const int col   = tid & 511;
    const int rbase = (tid >> 9) * 64;
    const int cb    = (bid & 3) * 512;
    float s1 = 0.f, s2 = 0.f, s3 = 0.f;
    for (int r = rbase; r < rbase + 64; ++r) {
      const float q = qLds[r];
      const float x = X[(size_t)(r0 + r) * KDIM + col];
      s1 += x; s2 += x * x; s3 += q * x;
    }
    atomicAdd(&colS1[cb + col], s1);
    atomicAdd(&colS2[cb + col], s2);
    atomicAdd(&colS3[cb + col], s3);
  }
  if (tid < BM) {   // 32-slot spread qsums (16 blocks/address)
    double q = (double)qLds[tid];
    double q2 = q * q;
    #pragma unroll
    for (int m = 1; m < 64; m <<= 1) {
      q  += __shfl_xor(q,  m, 64);
      q2 += __shfl_xor(q2, m, 64);
    }
    if ((tid & 63) == 0) {
      atomicAdd(&qsumsA[(bid & 31) * 2],     q);
      atomicAdd(&qsumsA[(bid & 31) * 2 + 1], q2);
    }
  }
}

// ---------------- finalize per-feature mean / inv_std ----------------
__global__ void finalize_kernel(const float* __restrict__ colS1, const float* __restrict__ colS2,
                                const float* __restrict__ colS3, const double* __restrict__ qsumsA,
                                const float* __restrict__ C2, const float* __restrict__ C3,
                                float* __restrict__ mean, float* __restrict__ inv_std) {
  __shared__ double sQ[2];
  if (threadIdx.x == 0) {
    double a = 0.0, b = 0.0;
    for (int i = 0; i < 32; ++i) { a += qsumsA[2 * i]; b += qsumsA[2 * i + 1]; }
    sQ[0] = a; sQ[1] = b;
  }
  __syncthreads();
  const int k = blockIdx.x * blockDim.x + threadIdx.x;
  if (k >= KDIM) return;
  const double invN = 1.0 / (double)NROWS;
  const double meanQ = sQ[0] * invN;
  const double varQ  = sQ[1] * invN - meanQ * meanQ;
  const float meanX = (colS1[k] + colS1[k + 512] + colS1[k + 1024] + colS1[k + 1536]) * (float)invN;
  const float s2    = (colS2[k] + colS2[k + 512] + colS2[k + 1024] + colS2[k + 1536]) * (float)invN;
  const float s3    = (colS3[k] + colS3[k + 512] + colS3[k + 1024] + colS3[k + 1536]) * (float)invN;
  const float varX  = s2 - meanX * meanX;
  const float covQX = s3 - (float)meanQ * meanX;
  const float c2 = C2[k];
  const float c3 = C3[0];
  const float m = (float)meanQ + c2 * meanX + c3;
  const float v = (float)varQ + c2 * c2 * varX + 2.0f * c2 * covQX;
  mean[k] = m;
  inv_std[k] = 1.0f / sqrtf(v + BN_EPS);
}

// ---------------- normalize + write ----------------
__global__ __launch_bounds__(256)
void normalize_kernel(const float* __restrict__ X, const float* __restrict__ quad,
                      const float* __restrict__ C2, const float* __restrict__ C3,
                      const float* __restrict__ mean, const float* __restrict__ inv_std,
                      float* __restrict__ out) {
  const int idx = blockIdx.x * blockDim.x + threadIdx.x;  // float4 index
  const int n = idx >> 7;
  const int j4 = idx & 127;
  const float q = quad[n];
  const float c3 = C3[0];
  const float4 x  = *(const float4*)&X[(size_t)idx * 4];
  const float4 c2 = *(const float4*)&C2[j4 * 4];
  const float4 m  = *(const float4*)&mean[j4 * 4];
  const float4 iv = *(const float4*)&inv_std[j4 * 4];
  float4 o;
  o.x = (q + c2.x * x.x + c3 - m.x) * iv.x;
  o.y = (q + c2.y * x.y + c3 - m.y) * iv.y;
  o.z = (q + c2.z * x.z + c3 - m.z) * iv.z;
  o.w = (q + c2.w * x.w + c3 - m.w) * iv.w;
  *(float4*)&out[(size_t)idx * 4] = o;
}

extern "C" void kernel_launch(void* const* d_in, const int* in_sizes, int n_in,
                              void* d_out, int out_size, void* d_ws, size_t ws_size,
                              hipStream_t stream) {
  const float* X  = (const float*)d_in[0];
  const float* C1 = (const float*)d_in[1];
  const float* C2 = (const float*)d_in[2];
  const float* C3 = (const float*)d_in[3];
  float* out = (float*)d_out;

  char* ws = (char*)d_ws;
  float*  quad    = (float*)ws;                           // 262144 B
  float*  colS1   = (float*)(ws + 262144);                // 4 copies x 512 f
  float*  colS2   = (float*)(ws + 262144 + 8192);
  float*  colS3   = (float*)(ws + 262144 + 16384);
  double* qsumsA  = (double*)(ws + 262144 + 24576);       // 32 x {q, q2}
  float*  mean    = (float*)(ws + 262144 + 25088);
  float*  inv_std = (float*)(ws + 262144 + 27136);
  short8* c1tH    = (short8*)(ws + 294912);               // 512 KB, 16B-aligned

  hipMemsetAsync(colS1, 0, 24576 + 512, stream);

  prep_c1<<<128, 256, 0, stream>>>(C1, c1tH);
  quad_kernel<<<NROWS / BM, 1024, 0, stream>>>(X, c1tH, quad,
                                               colS1, colS2, colS3, qsumsA);
  finalize_kernel<<<2, 256, 0, stream>>>(colS1, colS2, colS3, qsumsA, C2, C3, mean, inv_std);
  normalize_kernel<<<(NROWS * (KDIM / 4)) / 256, 256, 0, stream>>>(
      X, quad, C2, C3, mean, inv_std, out);
}